// Round 2
// baseline (725.422 us; speedup 1.0000x reference)
//
#include <hip/hip_runtime.h>

// Problem constants
#define BATCH 4
#define SEQ 4096
#define DM 1024
#define HALF_D 512            // DM/2 rope pairs
#define NROWS (BATCH * SEQ)   // 16384
#define NTILES_TRI 2080       // 64*65/2 lower-tri 64x64 tiles per batch

typedef _Float16 f16x8 __attribute__((ext_vector_type(8)));
typedef _Float16 f16x4 __attribute__((ext_vector_type(4)));
typedef _Float16 f16x2 __attribute__((ext_vector_type(2)));
typedef float f32x4 __attribute__((ext_vector_type(4)));

// ---------------- fp32 -> fp16 convert (8 elems/thread) ----------------
__global__ __launch_bounds__(256) void cvt_f32_f16(
    const float* __restrict__ src, _Float16* __restrict__ dst, int n8) {
  int i = blockIdx.x * 256 + threadIdx.x;
  if (i >= n8) return;
  const float4* s = (const float4*)src;
  float4 a = s[2 * i], b = s[2 * i + 1];
  f16x8 h;
  h[0] = (_Float16)a.x; h[1] = (_Float16)a.y;
  h[2] = (_Float16)a.z; h[3] = (_Float16)a.w;
  h[4] = (_Float16)b.x; h[5] = (_Float16)b.y;
  h[6] = (_Float16)b.z; h[7] = (_Float16)b.w;
  *(f16x8*)&dst[8 * i] = h;
}

// ---------------- RoPE apply in place on fp16 q or k ----------------
__global__ __launch_bounds__(256) void rope_apply(_Float16* __restrict__ T) {
  int idx = blockIdx.x * 256 + threadIdx.x;  // NROWS*HALF_D
  int row = idx >> 9;
  int i = idx & 511;
  int pos = row & (SEQ - 1);
  // theta = 10000^(-2*(i-1)/DM)  (faithful to reference's i-1)
  float theta = expf(-0.017988946039016f * ((float)i - 1.0f));
  float ang = (float)pos * theta;
  float c = cosf(ang), s = sinf(ang);
  f16x2 p = ((f16x2*)T)[idx];
  float e = (float)p[0], o = (float)p[1];
  p[0] = (_Float16)(e * c + o * s);
  p[1] = (_Float16)(o * c - e * s);
  ((f16x2*)T)[idx] = p;
}

// ---------------- shared NT GEMM: C[m][n] = sum_k A[m][k]*B[n][k] ----------------
// MODE 0: fp16 C row-major (Q/K projections)
// MODE 1: scores: scale 1/32 + causal mask, fp16 C into packed lower-tri tiles
// MODE 2: PV: A = packed-tri fp16 P, B = V^T, fp32 C, K limited to causal extent
// MODE 3: V projection with transposed output: Vt[b][d][m] fp16
template <int MODE>
__global__ __launch_bounds__(256) void gemm_nt(
    const _Float16* __restrict__ A, const _Float16* __restrict__ B,
    void* __restrict__ Cv, int K, int lda, int ldb, int ldc,
    long long strideA, long long strideB, long long strideC) {
  int bx = blockIdx.x, by = blockIdx.y, bz = blockIdx.z;
  if (MODE == 1 && bx > by) return;  // fully above diagonal
  A += (size_t)bz * strideA;
  B += (size_t)bz * strideB;

  __shared__ __align__(16) _Float16 sA[64 * 72];  // +8 pad
  __shared__ __align__(16) _Float16 sB[64 * 72];

  int tid = threadIdx.x;
  int lane = tid & 63, wave = tid >> 6;
  int wm = (wave & 1) * 32, wn = (wave >> 1) * 32;
  int r16 = lane & 15, quad = lane >> 4;
  int m0 = by * 64, n0 = bx * 64;

  f32x4 acc[2][2] = {};

  int nkt = (MODE == 2) ? (by + 1) : (K >> 6);

  for (int kt = 0; kt < nkt; ++kt) {
#pragma unroll
    for (int it = 0; it < 2; ++it) {
      int chunk = tid + it * 256;  // 512 chunks of 16B per tile
      int row = chunk >> 3, cc = chunk & 7;
      const _Float16* gA;
      if (MODE == 2) {
        // packed tri P: tile (by, kt); tile = 64x64 fp16 = 4096 halves
        gA = A + (size_t)(by * (by + 1) / 2 + kt) * 4096 + row * 64 + cc * 8;
      } else {
        gA = A + (size_t)(m0 + row) * lda + kt * 64 + cc * 8;
      }
      const _Float16* gB = B + (size_t)(n0 + row) * ldb + kt * 64 + cc * 8;
      *(int4*)(&sA[row * 72 + cc * 8]) = *(const int4*)gA;
      *(int4*)(&sB[row * 72 + cc * 8]) = *(const int4*)gB;
    }
    __syncthreads();

    f16x8 af[2][2], bfr[2][2];
#pragma unroll
    for (int mt = 0; mt < 2; ++mt)
#pragma unroll
      for (int ks = 0; ks < 2; ++ks) {
        af[mt][ks] =
            *(const f16x8*)&sA[(wm + mt * 16 + r16) * 72 + ks * 32 + quad * 8];
        bfr[mt][ks] =
            *(const f16x8*)&sB[(wn + mt * 16 + r16) * 72 + ks * 32 + quad * 8];
      }
#pragma unroll
    for (int ks = 0; ks < 2; ++ks)
#pragma unroll
      for (int mt = 0; mt < 2; ++mt)
#pragma unroll
        for (int nt = 0; nt < 2; ++nt)
          acc[mt][nt] = __builtin_amdgcn_mfma_f32_16x16x32_f16(
              af[mt][ks], bfr[nt][ks], acc[mt][nt], 0, 0, 0);
    __syncthreads();
  }

  if (MODE == 0) {
    _Float16* C = (_Float16*)Cv;
#pragma unroll
    for (int mt = 0; mt < 2; ++mt)
#pragma unroll
      for (int nt = 0; nt < 2; ++nt)
#pragma unroll
        for (int r = 0; r < 4; ++r) {
          int grow = m0 + wm + mt * 16 + quad * 4 + r;
          int gcol = n0 + wn + nt * 16 + r16;
          C[(size_t)grow * ldc + gcol] = (_Float16)acc[mt][nt][r];
        }
  } else if (MODE == 1) {
    _Float16* C = (_Float16*)Cv + (size_t)bz * strideC +
                  (size_t)(by * (by + 1) / 2 + bx) * 4096;
#pragma unroll
    for (int mt = 0; mt < 2; ++mt)
#pragma unroll
      for (int nt = 0; nt < 2; ++nt)
#pragma unroll
        for (int r = 0; r < 4; ++r) {
          int lr = wm + mt * 16 + quad * 4 + r;
          int lc = wn + nt * 16 + r16;
          float v = acc[mt][nt][r] * 0.03125f;  // 1/sqrt(1024)
          if (n0 + lc > m0 + lr) v = -3.0e4f;   // masked (never read anyway)
          C[lr * 64 + lc] = (_Float16)v;
        }
  } else if (MODE == 2) {
    float* C = (float*)Cv + (size_t)bz * strideC;
#pragma unroll
    for (int mt = 0; mt < 2; ++mt)
#pragma unroll
      for (int nt = 0; nt < 2; ++nt)
#pragma unroll
        for (int r = 0; r < 4; ++r) {
          int grow = m0 + wm + mt * 16 + quad * 4 + r;
          int gcol = n0 + wn + nt * 16 + r16;
          C[(size_t)grow * ldc + gcol] = acc[mt][nt][r];
        }
  } else {  // MODE 3: transposed V output -> Vt[b][d][m]
    _Float16* C = (_Float16*)Cv;
#pragma unroll
    for (int mt = 0; mt < 2; ++mt)
#pragma unroll
      for (int nt = 0; nt < 2; ++nt) {
        int gcol = n0 + wn + nt * 16 + r16;          // d
        int growb = m0 + wm + mt * 16 + quad * 4;    // m base (4 consecutive)
        int b = growb >> 12;
        int m = growb & (SEQ - 1);
        f16x4 t;
#pragma unroll
        for (int r = 0; r < 4; ++r) t[r] = (_Float16)acc[mt][nt][r];
        *(f16x4*)&C[((size_t)b * DM + gcol) * SEQ + m] = t;
      }
  }
}

// ---------------- row softmax on packed fp16 scores, fp16 P in place ----------------
__global__ __launch_bounds__(256) void softmax_rows(_Float16* __restrict__ Sp) {
  __shared__ float vals[SEQ];
  __shared__ float red[256];
  int row = blockIdx.x;  // 0..NROWS-1
  int b = row >> 12;
  int q = row & (SEQ - 1);
  int i = q >> 6, r = q & 63;
  _Float16* base = Sp + (size_t)b * ((size_t)NTILES_TRI * 4096) +
                   (size_t)(i * (i + 1) / 2) * 4096 + (size_t)r * 64;
  int tid = threadIdx.x;
  int Kv = q + 1;
  float m = -__builtin_inff();
  for (int k = tid; k < Kv; k += 256) {
    float v = (float)base[(k >> 6) * 4096 + (k & 63)];
    vals[k] = v;
    m = fmaxf(m, v);
  }
  red[tid] = m;
  __syncthreads();
  for (int s = 128; s > 0; s >>= 1) {
    if (tid < s) red[tid] = fmaxf(red[tid], red[tid + s]);
    __syncthreads();
  }
  m = red[0];
  __syncthreads();
  float l = 0.f;
  for (int k = tid; k < Kv; k += 256) {
    float e = expf(vals[k] - m);
    vals[k] = e;
    l += e;
  }
  red[tid] = l;
  __syncthreads();
  for (int s = 128; s > 0; s >>= 1) {
    if (tid < s) red[tid] += red[tid + s];
    __syncthreads();
  }
  float inv = 1.0f / red[0];
  int Kend = (i + 1) * 64;
  for (int k = tid; k < Kend; k += 256) {
    _Float16 p = (k < Kv) ? (_Float16)(vals[k] * inv) : (_Float16)0.f;
    base[(k >> 6) * 4096 + (k & 63)] = p;
  }
}

extern "C" void kernel_launch(void* const* d_in, const int* in_sizes, int n_in,
                              void* d_out, int out_size, void* d_ws,
                              size_t ws_size, hipStream_t stream) {
  const float* x = (const float*)d_in[0];
  const float* wq = (const float*)d_in[1];
  const float* wk = (const float*)d_in[2];
  const float* wv = (const float*)d_in[3];
  float* out = (float*)d_out;

  // Workspace layout (total ~97 MB):
  //   [0, 68157440)           : Sp (packed tri fp16 scores, B*2080*4096 halves)
  //     aliased early (dead before Sp written):
  //     [0, 33554432)         : xh (fp16 x)
  //     [33554432, 39845888)  : wqh, wkh, wvh (fp16 weights)
  //   [68157440, +33554432)   : vth (fp16 V^T, [B][DM][SEQ])
  char* ws = (char*)d_ws;
  _Float16* Sp = (_Float16*)ws;
  _Float16* xh = (_Float16*)ws;
  _Float16* wqh = (_Float16*)(ws + 33554432);
  _Float16* wkh = wqh + (size_t)DM * DM;
  _Float16* wvh = wkh + (size_t)DM * DM;
  _Float16* vth = (_Float16*)(ws + 68157440);
  // q, k live in d_out (2 x 33.5 MB = exactly out's 67 MB), dead before PV writes.
  _Float16* qh = (_Float16*)d_out;
  _Float16* kh = qh + (size_t)NROWS * DM;
  (void)ws_size; (void)in_sizes; (void)n_in; (void)out_size;

  // 1. fp32 -> fp16 converts
  cvt_f32_f16<<<8192, 256, 0, stream>>>(x, xh, NROWS * DM / 8);
  cvt_f32_f16<<<512, 256, 0, stream>>>(wq, wqh, DM * DM / 8);
  cvt_f32_f16<<<512, 256, 0, stream>>>(wk, wkh, DM * DM / 8);
  cvt_f32_f16<<<512, 256, 0, stream>>>(wv, wvh, DM * DM / 8);

  // 2. QKV projections (q,k into d_out; v transposed into vth)
  dim3 g0(DM / 64, NROWS / 64, 1);
  gemm_nt<0><<<g0, 256, 0, stream>>>(xh, wqh, qh, DM, DM, DM, DM, 0, 0, 0);
  gemm_nt<0><<<g0, 256, 0, stream>>>(xh, wkh, kh, DM, DM, DM, DM, 0, 0, 0);
  gemm_nt<3><<<g0, 256, 0, stream>>>(xh, wvh, vth, DM, DM, DM, 0, 0, 0, 0);

  // 3. RoPE q,k in place
  rope_apply<<<NROWS * HALF_D / 256, 256, 0, stream>>>(qh);
  rope_apply<<<NROWS * HALF_D / 256, 256, 0, stream>>>(kh);

  // 4. scores (causal lower-tri tiles only, fp16 packed)
  gemm_nt<1><<<dim3(SEQ / 64, SEQ / 64, BATCH), 256, 0, stream>>>(
      qh, kh, Sp, DM, DM, DM, 64, (long long)SEQ * DM, (long long)SEQ * DM,
      (long long)NTILES_TRI * 4096);

  // 5. softmax rows -> fp16 P in place
  softmax_rows<<<NROWS, 256, 0, stream>>>(Sp);

  // 6. O = P @ V  (A = packed P, B = V^T, causal K-limit)
  gemm_nt<2><<<dim3(DM / 64, SEQ / 64, BATCH), 256, 0, stream>>>(
      Sp, vth, out, SEQ, 0, SEQ, DM, (long long)NTILES_TRI * 4096,
      (long long)DM * SEQ, (long long)SEQ * DM);
}

// Round 3
// 699.499 us; speedup vs baseline: 1.0371x; 1.0371x over previous
//
#include <hip/hip_runtime.h>

// Problem constants
#define BATCH 4
#define SEQ 4096
#define DM 1024
#define HALF_D 512             // DM/2 rope pairs
#define NROWS (BATCH * SEQ)    // 16384
#define NT128 528              // 32*33/2 lower-tri 128x128 tiles per batch
#define TILE_ELE 16384         // 128*128

typedef _Float16 f16x8 __attribute__((ext_vector_type(8)));
typedef _Float16 f16x4 __attribute__((ext_vector_type(4)));
typedef _Float16 f16x2 __attribute__((ext_vector_type(2)));
typedef float f32x4 __attribute__((ext_vector_type(4)));

#define AS1(p) ((const __attribute__((address_space(1))) void*)(p))
#define AS3(p) ((__attribute__((address_space(3))) void*)(p))

// ---------------- fp32 -> fp16 convert (8 elems/thread) ----------------
__global__ __launch_bounds__(256) void cvt_f32_f16(
    const float* __restrict__ src, _Float16* __restrict__ dst, int n8) {
  int i = blockIdx.x * 256 + threadIdx.x;
  if (i >= n8) return;
  const float4* s = (const float4*)src;
  float4 a = s[2 * i], b = s[2 * i + 1];
  f16x8 h;
  h[0] = (_Float16)a.x; h[1] = (_Float16)a.y;
  h[2] = (_Float16)a.z; h[3] = (_Float16)a.w;
  h[4] = (_Float16)b.x; h[5] = (_Float16)b.y;
  h[6] = (_Float16)b.z; h[7] = (_Float16)b.w;
  *(f16x8*)&dst[8 * i] = h;
}

// ---------------- RoPE apply in place on fp16 q or k ----------------
__global__ __launch_bounds__(256) void rope_apply(_Float16* __restrict__ T) {
  int idx = blockIdx.x * 256 + threadIdx.x;  // NROWS*HALF_D
  int row = idx >> 9;
  int i = idx & 511;
  int pos = row & (SEQ - 1);
  float theta = expf(-0.017988946039016f * ((float)i - 1.0f));  // 10000^(-2(i-1)/DM)
  float ang = (float)pos * theta;
  float c = cosf(ang), s = sinf(ang);
  f16x2 p = ((f16x2*)T)[idx];
  float e = (float)p[0], o = (float)p[1];
  p[0] = (_Float16)(e * c + o * s);
  p[1] = (_Float16)(o * c - e * s);
  ((f16x2*)T)[idx] = p;
}

// ---------------- m97-style NT GEMM: C[m][n] = sum_k A[m][k]*B[n][k] ----------------
// 128x128 tile, BK=64, 256 threads (4 waves, each 64x64 via 4x4 16x16x32 frags),
// global_load_lds width=16, unpadded LDS (contiguous chunk order).
// MODE 0: fp16 C row-major (Q/K projections)
// MODE 1: scores: scale 1/32, fp16 C into packed lower-tri 128x128 tiles (no mask
//         needed: softmax never reads k>q and zero-fills P to the 128-boundary)
// MODE 2: PV: A = packed-tri fp16 P, B = V^T, fp32 C, K limited to (by+1)*128
// MODE 3: V projection with transposed output: Vt[b][d][m] fp16
template <int MODE>
__global__ __launch_bounds__(256) void gemm128(
    const _Float16* __restrict__ A, const _Float16* __restrict__ B,
    void* __restrict__ Cv, int K, int lda, int ldb, int ldc,
    long long strideA, long long strideB, long long strideC) {
  int bx = blockIdx.x, bz = blockIdx.z;
  int by = (MODE == 2) ? (31 - blockIdx.y) : blockIdx.y;  // heavy tiles first
  if (MODE == 1 && bx > by) return;  // fully above diagonal
  A += (size_t)bz * strideA;
  B += (size_t)bz * strideB;

  __shared__ __align__(16) _Float16 sA[128 * 64];  // 16 KB, row-major stride 64
  __shared__ __align__(16) _Float16 sB[128 * 64];

  const int tid = threadIdx.x;
  const int lane = tid & 63, wave = tid >> 6;
  const int wm = (wave & 1) * 64, wn = (wave >> 1) * 64;
  const int r16 = lane & 15, quad = lane >> 4;
  const int m0 = by * 128, n0 = bx * 128;
  const int triBase = by * (by + 1) / 2;

  f32x4 acc[4][4] = {};

  const int nkt = (MODE == 2) ? (by + 1) * 2 : (K >> 6);

  for (int kt = 0; kt < nkt; ++kt) {
    // ---- stage A,B tiles (128x64 fp16 = 16 KB each) via global_load_lds ----
#pragma unroll
    for (int j = 0; j < 4; ++j) {
      int c = j * 256 + tid;          // chunk 0..1023 (16 B each)
      int row = c >> 3, col = c & 7;  // row 0..127, 16B-col 0..7
      const _Float16* gA;
      if (MODE == 2) {
        gA = A + (size_t)(triBase + (kt >> 1)) * TILE_ELE + row * 128 +
             (kt & 1) * 64 + col * 8;
      } else {
        gA = A + (size_t)(m0 + row) * lda + kt * 64 + col * 8;
      }
      const _Float16* gB = B + (size_t)(n0 + row) * ldb + kt * 64 + col * 8;
      // LDS dest: wave-uniform base + lane*16 (chunk order == LDS linear order)
      __builtin_amdgcn_global_load_lds(AS1(gA), AS3(&sA[(j * 256 + wave * 64) * 8]), 16, 0, 0);
      __builtin_amdgcn_global_load_lds(AS1(gB), AS3(&sB[(j * 256 + wave * 64) * 8]), 16, 0, 0);
    }
    __syncthreads();

    // ---- MFMA over the two 32-wide k-halves ----
#pragma unroll
    for (int ks = 0; ks < 2; ++ks) {
      f16x8 af[4], bf[4];
#pragma unroll
      for (int i = 0; i < 4; ++i) {
        af[i] = *(const f16x8*)&sA[(wm + i * 16 + r16) * 64 + ks * 32 + quad * 8];
        bf[i] = *(const f16x8*)&sB[(wn + i * 16 + r16) * 64 + ks * 32 + quad * 8];
      }
#pragma unroll
      for (int mi = 0; mi < 4; ++mi)
#pragma unroll
        for (int ni = 0; ni < 4; ++ni)
          acc[mi][ni] = __builtin_amdgcn_mfma_f32_16x16x32_f16(
              af[mi], bf[ni], acc[mi][ni], 0, 0, 0);
    }
    __syncthreads();
  }

  // ---- epilogues ----
  if (MODE == 0) {
    _Float16* C = (_Float16*)Cv;
#pragma unroll
    for (int mi = 0; mi < 4; ++mi)
#pragma unroll
      for (int ni = 0; ni < 4; ++ni)
#pragma unroll
        for (int r = 0; r < 4; ++r) {
          int grow = m0 + wm + mi * 16 + quad * 4 + r;
          int gcol = n0 + wn + ni * 16 + r16;
          C[(size_t)grow * ldc + gcol] = (_Float16)acc[mi][ni][r];
        }
  } else if (MODE == 1) {
    _Float16* C = (_Float16*)Cv + (size_t)bz * strideC +
                  (size_t)(triBase + bx) * TILE_ELE;
#pragma unroll
    for (int mi = 0; mi < 4; ++mi)
#pragma unroll
      for (int ni = 0; ni < 4; ++ni)
#pragma unroll
        for (int r = 0; r < 4; ++r) {
          int lr = wm + mi * 16 + quad * 4 + r;
          int lc = wn + ni * 16 + r16;
          C[lr * 128 + lc] = (_Float16)(acc[mi][ni][r] * 0.03125f);
        }
  } else if (MODE == 2) {
    float* C = (float*)Cv + (size_t)bz * strideC;
#pragma unroll
    for (int mi = 0; mi < 4; ++mi)
#pragma unroll
      for (int ni = 0; ni < 4; ++ni)
#pragma unroll
        for (int r = 0; r < 4; ++r) {
          int grow = m0 + wm + mi * 16 + quad * 4 + r;
          int gcol = n0 + wn + ni * 16 + r16;
          C[(size_t)grow * ldc + gcol] = acc[mi][ni][r];
        }
  } else {  // MODE 3: Vt[b][d][m]
    _Float16* C = (_Float16*)Cv;
#pragma unroll
    for (int mi = 0; mi < 4; ++mi)
#pragma unroll
      for (int ni = 0; ni < 4; ++ni) {
        int gcol = n0 + wn + ni * 16 + r16;        // d
        int growb = m0 + wm + mi * 16 + quad * 4;  // m base, 4 consecutive
        int b = growb >> 12;
        int m = growb & (SEQ - 1);
        f16x4 t;
#pragma unroll
        for (int r = 0; r < 4; ++r) t[r] = (_Float16)acc[mi][ni][r];
        *(f16x4*)&C[((size_t)b * DM + gcol) * SEQ + m] = t;
      }
  }
}

// ---------------- row softmax on packed fp16 scores, fp16 P in place ----------------
__global__ __launch_bounds__(256) void softmax_rows(_Float16* __restrict__ Sp) {
  __shared__ float vals[SEQ];
  __shared__ float red[256];
  int row = blockIdx.x;  // 0..NROWS-1
  int b = row >> 12;
  int q = row & (SEQ - 1);
  int i = q >> 7, r = q & 127;
  _Float16* base = Sp + (size_t)b * ((size_t)NT128 * TILE_ELE) +
                   (size_t)(i * (i + 1) / 2) * TILE_ELE + (size_t)r * 128;
  int tid = threadIdx.x;
  int Kv = q + 1;
  float m = -__builtin_inff();
  // vectorized read of full 8-groups
  for (int kb = tid * 8; kb + 8 <= Kv; kb += 2048) {
    f16x8 v8 = *(const f16x8*)&base[(kb >> 7) * TILE_ELE + (kb & 127)];
#pragma unroll
    for (int t = 0; t < 8; ++t) {
      float v = (float)v8[t];
      vals[kb + t] = v;
      m = fmaxf(m, v);
    }
  }
  if (tid == 0) {  // tail (Kv % 8 elements)
    for (int k = Kv & ~7; k < Kv; ++k) {
      float v = (float)base[(k >> 7) * TILE_ELE + (k & 127)];
      vals[k] = v;
      m = fmaxf(m, v);
    }
  }
  red[tid] = m;
  __syncthreads();
  for (int s = 128; s > 0; s >>= 1) {
    if (tid < s) red[tid] = fmaxf(red[tid], red[tid + s]);
    __syncthreads();
  }
  m = red[0];
  __syncthreads();
  float l = 0.f;
  for (int k = tid; k < Kv; k += 256) {
    float e = __expf(vals[k] - m);
    vals[k] = e;
    l += e;
  }
  red[tid] = l;
  __syncthreads();
  for (int s = 128; s > 0; s >>= 1) {
    if (tid < s) red[tid] += red[tid + s];
    __syncthreads();
  }
  float inv = 1.0f / red[0];
  int Kend = (i + 1) * 128;  // zero-fill to tile boundary (covers PV K-extent)
  for (int kb = tid * 8; kb < Kend; kb += 2048) {
    f16x8 p;
#pragma unroll
    for (int t = 0; t < 8; ++t) {
      int k = kb + t;
      p[t] = (k < Kv) ? (_Float16)(vals[k] * inv) : (_Float16)0.f;
    }
    *(f16x8*)&base[(kb >> 7) * TILE_ELE + (kb & 127)] = p;
  }
}

extern "C" void kernel_launch(void* const* d_in, const int* in_sizes, int n_in,
                              void* d_out, int out_size, void* d_ws,
                              size_t ws_size, hipStream_t stream) {
  const float* x = (const float*)d_in[0];
  const float* wq = (const float*)d_in[1];
  const float* wk = (const float*)d_in[2];
  const float* wv = (const float*)d_in[3];
  float* out = (float*)d_out;

  // Workspace layout (~98 MiB):
  //   [0, 69206016)            : Sp (packed tri fp16 scores, B*528*16384 halves)
  //     aliased early (dead before Sp written):
  //     [0, 33554432)          : xh (fp16 x)
  //     [33554432, 39845888)   : wqh, wkh, wvh (fp16 weights)
  //   [69206016, +33554432)    : vth (fp16 V^T, [B][DM][SEQ])
  char* ws = (char*)d_ws;
  _Float16* Sp = (_Float16*)ws;
  _Float16* xh = (_Float16*)ws;
  _Float16* wqh = (_Float16*)(ws + 33554432);
  _Float16* wkh = wqh + (size_t)DM * DM;
  _Float16* wvh = wkh + (size_t)DM * DM;
  _Float16* vth = (_Float16*)(ws + 69206016);
  // q, k live in d_out (2 x 33.5 MB = exactly out's 67 MB), dead before PV writes.
  _Float16* qh = (_Float16*)d_out;
  _Float16* kh = qh + (size_t)NROWS * DM;
  (void)ws_size; (void)in_sizes; (void)n_in; (void)out_size;

  // 1. fp32 -> fp16 converts
  cvt_f32_f16<<<8192, 256, 0, stream>>>(x, xh, NROWS * DM / 8);
  cvt_f32_f16<<<512, 256, 0, stream>>>(wq, wqh, DM * DM / 8);
  cvt_f32_f16<<<512, 256, 0, stream>>>(wk, wkh, DM * DM / 8);
  cvt_f32_f16<<<512, 256, 0, stream>>>(wv, wvh, DM * DM / 8);

  // 2. QKV projections (q,k into d_out; v transposed into vth)
  dim3 g0(DM / 128, NROWS / 128, 1);
  gemm128<0><<<g0, 256, 0, stream>>>(xh, wqh, qh, DM, DM, DM, DM, 0, 0, 0);
  gemm128<0><<<g0, 256, 0, stream>>>(xh, wkh, kh, DM, DM, DM, DM, 0, 0, 0);
  gemm128<3><<<g0, 256, 0, stream>>>(xh, wvh, vth, DM, DM, DM, 0, 0, 0, 0);

  // 3. RoPE q,k in place
  rope_apply<<<NROWS * HALF_D / 256, 256, 0, stream>>>(qh);
  rope_apply<<<NROWS * HALF_D / 256, 256, 0, stream>>>(kh);

  // 4. scores (causal lower-tri 128-tiles, fp16 packed, scaled)
  gemm128<1><<<dim3(SEQ / 128, SEQ / 128, BATCH), 256, 0, stream>>>(
      qh, kh, Sp, DM, DM, DM, 128, (long long)SEQ * DM, (long long)SEQ * DM,
      (long long)NT128 * TILE_ELE);

  // 5. softmax rows -> fp16 P in place
  softmax_rows<<<NROWS, 256, 0, stream>>>(Sp);

  // 6. O = P @ V  (A = packed P, B = V^T, causal K-limit, heavy blocks first)
  gemm128<2><<<dim3(DM / 128, SEQ / 128, BATCH), 256, 0, stream>>>(
      Sp, vth, out, SEQ, 0, SEQ, DM, (long long)NT128 * TILE_ELE,
      (long long)DM * SEQ, (long long)SEQ * DM);
}